// Round 2
// baseline (926.671 us; speedup 1.0000x reference)
//
#include <hip/hip_runtime.h>

// ---------------------------------------------------------------------------
// SlidingAttention: B=8 S=4096 E=1024 H=8 W=128 D=128, window look-around 1.
// fp32 inputs/outputs (per reference); bf16 intermediates in ws, fp32 accum.
// Pipeline:
//   proj_kernel x3 : q/k/v = x @ W^T per head  -> ws as [B,H,S,D] bf16
//   attn_kernel    : per (b,h,window) tile, full 384-key row in regs,
//                    O^T orientation; O overwrites q region in-place [B,H,S,D]
//   outproj_kernel : out = O @ Wo^T + bo       -> [B,S,E] fp32
// ws layout: q (64MiB) | k (64MiB) | v (64MiB)   = 192 MiB total
// ---------------------------------------------------------------------------

typedef __attribute__((ext_vector_type(8))) short short8;
typedef __attribute__((ext_vector_type(4))) short short4v;
typedef __attribute__((ext_vector_type(4))) float float4v;

#define MFMA16(a, b, c) __builtin_amdgcn_mfma_f32_16x16x32_bf16((a), (b), (c), 0, 0, 0)

constexpr int NW_ = 32;    // windows per sequence
constexpr int LD_ = 136;   // padded LDS row stride (bf16 elems): 272B, 16B-aligned

__device__ __forceinline__ unsigned short f2bf(float f) {
  unsigned u = __builtin_bit_cast(unsigned, f);
  u += 0x7fffu + ((u >> 16) & 1u);          // RNE
  return (unsigned short)(u >> 16);
}

// pack 8 fp32 -> 8 bf16
__device__ __forceinline__ short8 pack8(float4v a0, float4v a1) {
  short8 s;
  for (int j = 0; j < 4; ++j) { s[j] = (short)f2bf(a0[j]); s[4 + j] = (short)f2bf(a1[j]); }
  return s;
}

// ---------------------------------------------------------------------------
// Per-head projection: rows r=(b,s,h) are flat-contiguous in x (r*128+d).
// out[(b*8+h)*4096 + s][o]  ([B,H,S,D] bf16).  M=262144, N=K=128.
// ---------------------------------------------------------------------------
__global__ __launch_bounds__(256) void proj_kernel(
    const float* __restrict__ x, const float* __restrict__ w,
    unsigned short* __restrict__ out) {
  __shared__ unsigned short lA[128 * LD_];
  __shared__ unsigned short lB[128 * LD_];
  const int tid = threadIdx.x;
  const long m0 = (long)blockIdx.x * 128;

  for (int idx = tid; idx < 2048; idx += 256) {   // A tile: 128x128 fp32 -> bf16
    const float* src = x + m0 * 128 + (long)idx * 8;
    float4v a0 = *(const float4v*)(src);
    float4v a1 = *(const float4v*)(src + 4);
    *(short8*)&lA[(idx >> 4) * LD_ + (idx & 15) * 8] = pack8(a0, a1);
  }
  for (int idx = tid; idx < 2048; idx += 256) {   // W tile [n][k] (= B^T, NT layout)
    const float* src = w + idx * 8;
    float4v a0 = *(const float4v*)(src);
    float4v a1 = *(const float4v*)(src + 4);
    *(short8*)&lB[(idx >> 4) * LD_ + (idx & 15) * 8] = pack8(a0, a1);
  }
  __syncthreads();

  const int wv = tid >> 6, L = tid & 63, lr = L & 15, lg = L >> 4;
  const int wm = wv >> 1, wn = wv & 1;   // wave -> 64x64 quadrant
  float4v acc[4][4];
  for (int a = 0; a < 4; ++a)
    for (int b = 0; b < 4; ++b)
      for (int r = 0; r < 4; ++r) acc[a][b][r] = 0.f;

  for (int ks = 0; ks < 4; ++ks) {
    short8 af[4], bf[4];
    for (int mt = 0; mt < 4; ++mt)
      af[mt] = *(const short8*)&lA[(wm * 64 + mt * 16 + lr) * LD_ + ks * 32 + lg * 8];
    for (int nt = 0; nt < 4; ++nt)
      bf[nt] = *(const short8*)&lB[(wn * 64 + nt * 16 + lr) * LD_ + ks * 32 + lg * 8];
    for (int mt = 0; mt < 4; ++mt)
      for (int nt = 0; nt < 4; ++nt)
        acc[mt][nt] = MFMA16(af[mt], bf[nt], acc[mt][nt]);
  }
  __syncthreads();
  for (int mt = 0; mt < 4; ++mt)          // stage C (bf16) back into lA
    for (int nt = 0; nt < 4; ++nt)
      for (int r = 0; r < 4; ++r)
        lA[(wm * 64 + mt * 16 + lg * 4 + r) * LD_ + wn * 64 + nt * 16 + lr] =
            f2bf(acc[mt][nt][r]);
  __syncthreads();
  for (int idx = tid; idx < 2048; idx += 256) {   // coalesced permuted store
    int r = idx >> 4, c = idx & 15;
    long row = m0 + r;                             // row = (b*S+s)*H + h
    int b = (int)(row >> 15), s = (int)((row >> 3) & 4095), h = (int)(row & 7);
    long g = ((long)(b * 8 + h) * 4096 + s) * 128 + c * 8;
    *(short8*)(out + g) = *(const short8*)&lA[r * LD_ + c * 8];
  }
}

// ---------------------------------------------------------------------------
// Attention: block = (b,h,window i), 512 threads = 8 waves, wave w owns
// 16 q-rows sq in [w*16, w*16+16).  S^T = K·Q^T per chunk (lane owns column
// sq = w*16 + (lane&15); column spread over 4 quads -> shfl_xor 16/32).
// O^T = V^T·P^T so both PV operands are contiguous LDS reads and the global
// store packs 4 consecutive d.  O overwrites qp in place.
// ---------------------------------------------------------------------------
__global__ __launch_bounds__(512, 2) void attn_kernel(
    const unsigned short* __restrict__ qp, const unsigned short* __restrict__ kp,
    const unsigned short* __restrict__ vp, unsigned short* __restrict__ op) {
  __shared__ unsigned short lQ[128 * LD_];
  __shared__ unsigned short lK[128 * LD_];   // K chunks, then reused for P
  __shared__ unsigned short lV[128 * LD_];   // V^T chunk
  const int tid = threadIdx.x;
  const int bid = blockIdx.x;
  const int b = bid >> 8, h = (bid >> 5) & 7, i = bid & 31;
  const long base = (long)(b * 8 + h) * (4096L * 128);

  for (int idx = tid; idx < 2048; idx += 512)
    *(short8*)&lQ[(idx >> 4) * LD_ + (idx & 15) * 8] =
        *(const short8*)(qp + base + (long)i * 16384 + (long)idx * 8);

  const int wv = tid >> 6, L = tid & 63, lr = L & 15, lg = L >> 4;
  const bool valid[3] = {i > 0, true, i < NW_ - 1};
  float4v Sacc[3][8];

  // ---- phase 1: S^T chunks (full 384-key row kept in registers) ----
  for (int j = 0; j < 3; ++j) {
    if (!valid[j]) continue;               // block-uniform
    const int jw = i - 1 + j;
    __syncthreads();                       // lQ staged / prev chunk's lK reads done
    for (int idx = tid; idx < 2048; idx += 512)
      *(short8*)&lK[(idx >> 4) * LD_ + (idx & 15) * 8] =
          *(const short8*)(kp + base + (long)jw * 16384 + (long)idx * 8);
    __syncthreads();
    for (int mt = 0; mt < 8; ++mt)
      for (int r = 0; r < 4; ++r) Sacc[j][mt][r] = 0.f;
    for (int ks = 0; ks < 4; ++ks) {
      short8 bq = *(const short8*)&lQ[(wv * 16 + lr) * LD_ + ks * 32 + lg * 8];
      for (int mt = 0; mt < 8; ++mt) {
        short8 ak = *(const short8*)&lK[(mt * 16 + lr) * LD_ + ks * 32 + lg * 8];
        Sacc[j][mt] = MFMA16(ak, bq, Sacc[j][mt]);
      }
    }
  }

  // ---- softmax stats (column sq spread over 4 quads) ----
  float mraw = -3.0e38f;
  for (int j = 0; j < 3; ++j) {
    if (!valid[j]) continue;
    for (int mt = 0; mt < 8; ++mt)
      for (int r = 0; r < 4; ++r) mraw = fmaxf(mraw, Sacc[j][mt][r]);
  }
  mraw = fmaxf(mraw, __shfl_xor(mraw, 16));
  mraw = fmaxf(mraw, __shfl_xor(mraw, 32));
  const float csc = 0.08838834764831845f * 1.4426950408889634f;  // scale*log2(e)
  const float mm = mraw * csc;
  float lsum = 0.f;
  float4v Oacc[8];
  for (int mt = 0; mt < 8; ++mt)
    for (int r = 0; r < 4; ++r) Oacc[mt][r] = 0.f;

  // ---- phase 2: P write + V^T load + PV per chunk ----
  for (int j = 0; j < 3; ++j) {
    if (!valid[j]) continue;
    const int jw = i - 1 + j;
    __syncthreads();                       // prev lK/lV consumers done
    for (int mt = 0; mt < 8; ++mt) {       // P: 4 consecutive sk per lane -> b64
      short4v pk;
      for (int r = 0; r < 4; ++r) {
        float p = exp2f(Sacc[j][mt][r] * csc - mm);
        lsum += p;
        pk[r] = (short)f2bf(p);
      }
      *(short4v*)&lK[(wv * 16 + lr) * LD_ + mt * 16 + lg * 4] = pk;
    }
    for (int idx = tid; idx < 1024; idx += 512) {   // V -> V^T (paired b32 writes)
      int pr = idx & 63, c = idx >> 6;
      const unsigned short* src = vp + base + (long)jw * 16384 + (long)(2 * pr) * 128 + c * 8;
      short8 v0 = *(const short8*)(src);
      short8 v1 = *(const short8*)(src + 128);
      for (int jj = 0; jj < 8; ++jj) {
        unsigned val = ((unsigned)(unsigned short)v0[jj]) |
                       (((unsigned)(unsigned short)v1[jj]) << 16);
        *(unsigned*)&lV[(c * 8 + jj) * LD_ + 2 * pr] = val;
      }
    }
    __syncthreads();
    for (int ks = 0; ks < 4; ++ks) {
      short8 bp = *(const short8*)&lK[(wv * 16 + lr) * LD_ + ks * 32 + lg * 8];
      for (int mt = 0; mt < 8; ++mt) {
        short8 av = *(const short8*)&lV[(mt * 16 + lr) * LD_ + ks * 32 + lg * 8];
        Oacc[mt] = MFMA16(av, bp, Oacc[mt]);
      }
    }
  }

  lsum += __shfl_xor(lsum, 16);
  lsum += __shfl_xor(lsum, 32);
  const float rl = 1.f / lsum;
  const long obase = base + (long)i * 16384;
  for (int mt = 0; mt < 8; ++mt) {         // O^T: 4 consecutive d per lane -> b64 store
    short4v ok;
    for (int r = 0; r < 4; ++r) ok[r] = (short)f2bf(Oacc[mt][r] * rl);
    *(short4v*)(op + obase + (long)(wv * 16 + lr) * 128 + mt * 16 + lg * 4) = ok;
  }
}

// ---------------------------------------------------------------------------
// out[b*S+s][e] = sum_{h,d} O[b,h,s,d] * Wo[e][h*128+d] + bo[e]   (fp32 out)
// M=32768, N=K=1024; 128x128 tiles, BK=64.
// ---------------------------------------------------------------------------
constexpr int LDK_ = 72;
__global__ __launch_bounds__(256) void outproj_kernel(
    const unsigned short* __restrict__ O, const float* __restrict__ Wo,
    const float* __restrict__ bo, float* __restrict__ out) {
  __shared__ unsigned short lA[128 * LDK_];
  __shared__ unsigned short lB[128 * LDK_];
  const int tid = threadIdx.x;
  const long m0 = (long)blockIdx.x * 128;
  const int n0 = blockIdx.y * 128;
  const int wv = tid >> 6, L = tid & 63, lr = L & 15, lg = L >> 4;
  const int wm = wv >> 1, wn = wv & 1;
  float4v acc[4][4];
  for (int a = 0; a < 4; ++a)
    for (int b = 0; b < 4; ++b)
      for (int r = 0; r < 4; ++r) acc[a][b][r] = 0.f;

  for (int kk = 0; kk < 1024; kk += 64) {
    const int hh = kk >> 7, d0 = kk & 127;    // 64-wide k-chunk stays within one head
    for (int idx = tid; idx < 1024; idx += 256) {
      int r = idx >> 3, c = idx & 7;
      long row = m0 + r;
      int b = (int)(row >> 12), s = (int)(row & 4095);
      *(short8*)&lA[r * LDK_ + c * 8] =
          *(const short8*)(O + (((long)(b * 8 + hh) * 4096 + s) * 128 + d0 + c * 8));
    }
    for (int idx = tid; idx < 1024; idx += 256) {
      int r = idx >> 3, c = idx & 7;
      const float* src = Wo + ((long)(n0 + r) * 1024 + kk + c * 8);
      float4v a0 = *(const float4v*)(src);
      float4v a1 = *(const float4v*)(src + 4);
      *(short8*)&lB[r * LDK_ + c * 8] = pack8(a0, a1);
    }
    __syncthreads();
    for (int ks = 0; ks < 2; ++ks) {
      short8 af[4], bf[4];
      for (int mt = 0; mt < 4; ++mt)
        af[mt] = *(const short8*)&lA[(wm * 64 + mt * 16 + lr) * LDK_ + ks * 32 + lg * 8];
      for (int nt = 0; nt < 4; ++nt)
        bf[nt] = *(const short8*)&lB[(wn * 64 + nt * 16 + lr) * LDK_ + ks * 32 + lg * 8];
      for (int mt = 0; mt < 4; ++mt)
        for (int nt = 0; nt < 4; ++nt)
          acc[mt][nt] = MFMA16(af[mt], bf[nt], acc[mt][nt]);
    }
    __syncthreads();
  }

  // direct fp32 stores in C-layout: each quad stores 16 consecutive dwords (64B)
  for (int nt = 0; nt < 4; ++nt) {
    float bv = bo[n0 + wn * 64 + nt * 16 + lr];
    for (int mt = 0; mt < 4; ++mt)
      for (int r = 0; r < 4; ++r)
        out[(m0 + wm * 64 + mt * 16 + lg * 4 + r) * 1024 + n0 + wn * 64 + nt * 16 + lr] =
            acc[mt][nt][r] + bv;
  }
}

// ---------------------------------------------------------------------------
extern "C" void kernel_launch(void* const* d_in, const int* in_sizes, int n_in,
                              void* d_out, int out_size, void* d_ws, size_t ws_size,
                              hipStream_t stream) {
  const float* values = (const float*)d_in[0];
  const float* keys   = (const float*)d_in[1];
  const float* query  = (const float*)d_in[2];
  const float* Wv     = (const float*)d_in[3];
  const float* Wk     = (const float*)d_in[4];
  const float* Wq     = (const float*)d_in[5];
  const float* Wo     = (const float*)d_in[6];
  const float* bo     = (const float*)d_in[7];
  float* out = (float*)d_out;

  const size_t plane = 8UL * 8 * 4096 * 128;      // B*H*S*D = 33554432 elems
  unsigned short* qp = (unsigned short*)d_ws;
  unsigned short* kp = qp + plane;
  unsigned short* vp = kp + plane;

  proj_kernel<<<2048, 256, 0, stream>>>(query, Wq, qp);
  proj_kernel<<<2048, 256, 0, stream>>>(keys, Wk, kp);
  proj_kernel<<<2048, 256, 0, stream>>>(values, Wv, vp);
  attn_kernel<<<2048, 512, 0, stream>>>(qp, kp, vp, qp);     // O overwrites q region
  outproj_kernel<<<dim3(256, 8), 256, 0, stream>>>(qp, Wo, bo, out);
}